// Round 7
// baseline (174.731 us; speedup 1.0000x reference)
//
#include <hip/hip_runtime.h>
#include <hip/hip_cooperative_groups.h>

namespace cg = cooperative_groups;

#define EPS 1e-6

constexpr int B = 8, C = 256, T = 16000;
constexpr int T4 = T / 4;            // 4000
constexpr int NBLK = 125;            // blocks per batch
constexpr int TPB_T = 128;           // t-columns per block
constexpr int NT4 = 32;              // float4 groups per block (128/4)

typedef float f32x4 __attribute__((ext_vector_type(4)));

// Fused single-pass via cooperative grid sync — no flags, no polling, no
// per-window fences (R3/R5's pathology). Phase A: tile channel-sums + block
// scan + publish one aggregate. grid.sync(). Phase B: wave-parallel reduce of
// predecessor aggregates (<=124, 2KB, L2-hot). Phase C: normalize; the x
// re-read has tight per-block temporal locality (R3 measured FETCH ~= x read
// once => re-read served by cache).
__global__ __launch_bounds__(256)
void clnorm_coop(const float4* __restrict__ x4,
                 const float*  __restrict__ weight,
                 const float*  __restrict__ bias,
                 float4* __restrict__ y4,
                 double2* __restrict__ agg)          // [B*NBLK] in d_ws
{
    const int tid  = threadIdx.x;
    const int lane = tid & 63;
    const int wid  = tid >> 6;
    const int id   = blockIdx.x;
    const int b    = id / NBLK;
    const int blk  = id % NBLK;
    const int t4base = blk * NT4;

    const int t4 = tid & 31;          // float4 group within tile
    const int c0 = tid >> 5;          // 0..7, c stride 8

    const size_t xrow = (size_t)b * C;

    // ---- Phase A: per-t sums over channels (float4 over t) ----
    float4 s4 = {0.f,0.f,0.f,0.f}, q4 = {0.f,0.f,0.f,0.f};
#pragma unroll 8
    for (int i = 0; i < 32; ++i) {
        int c = c0 + 8 * i;
        float4 xv = x4[(xrow + c) * T4 + t4base + t4];
        s4.x += xv.x;       s4.y += xv.y;       s4.z += xv.z;       s4.w += xv.w;
        q4.x += xv.x*xv.x;  q4.y += xv.y*xv.y;  q4.z += xv.z*xv.z;  q4.w += xv.w*xv.w;
    }

    __shared__ float psum[8 * TPB_T], qsum[8 * TPB_T];
    ((float4*)psum)[c0 * NT4 + t4] = s4;
    ((float4*)qsum)[c0 * NT4 + t4] = q4;
    __syncthreads();

    // ---- block-local inclusive scan over 128 t values (double) ----
    __shared__ double csum[TPB_T], csum2[TPB_T];
    __shared__ double wtot[2], wtot2[2];
    double ds = 0.0, dq = 0.0;
    if (tid < TPB_T) {
        float fs = 0.f, fq = 0.f;
#pragma unroll
        for (int g = 0; g < 8; ++g) {
            fs += psum[g * TPB_T + tid];
            fq += qsum[g * TPB_T + tid];
        }
        ds = (double)fs; dq = (double)fq;
        for (int off = 1; off < 64; off <<= 1) {
            double u  = __shfl_up(ds, off);
            double u2 = __shfl_up(dq, off);
            if (lane >= off) { ds += u; dq += u2; }
        }
        if (lane == 63) { wtot[wid] = ds; wtot2[wid] = dq; }
    }
    __syncthreads();
    if (tid < TPB_T) {
        if (wid == 1) { ds += wtot[0]; dq += wtot2[0]; }
        csum[tid] = ds; csum2[tid] = dq;
    }
    __syncthreads();

    if (tid == 0)
        agg[id] = make_double2(wtot[0] + wtot[1], wtot2[0] + wtot2[1]);

    // ---- one grid-wide barrier (release/acquire handled by runtime) ----
    cg::this_grid().sync();

    // ---- Phase B: exclusive prefix of predecessor aggregates ----
    __shared__ double exsh[2];
    if (wid == 0) {
        double cS = 0.0, cQ = 0.0;
        const int base0 = b * NBLK;
        if (lane < blk) { double2 a = agg[base0 + lane];      cS += a.x; cQ += a.y; }
        int j2 = 64 + lane;
        if (j2 < blk)   { double2 a = agg[base0 + j2];        cS += a.x; cQ += a.y; }
        for (int o = 32; o; o >>= 1) { cS += __shfl_xor(cS, o); cQ += __shfl_xor(cQ, o); }
        if (lane == 0) { exsh[0] = cS; exsh[1] = cQ; }
    }
    __syncthreads();

    // ---- mean / istd for this block's 128 t values ----
    __shared__ float meanf[TPB_T], istdf[TPB_T];
    if (tid < TPB_T) {
        int t = blk * TPB_T + tid;
        double cs  = exsh[0] + csum[tid];
        double cq  = exsh[1] + csum2[tid];
        double cnt = (double)(t + 1) * (double)C;
        double mean = cs / cnt;
        double var  = cq / cnt - mean * mean;
        meanf[tid] = (float)mean;
        istdf[tid] = (float)(1.0 / sqrt(var + EPS));
    }
    __syncthreads();

    // ---- Phase C: normalize (x re-read cache-served; y nontemporal) ----
    const float4 mv = ((const float4*)meanf)[t4];
    const float4 iv = ((const float4*)istdf)[t4];
#pragma unroll 4
    for (int i = 0; i < 32; ++i) {
        int c = c0 + 8 * i;
        size_t idx = (xrow + c) * T4 + t4base + t4;
        float4 xv = x4[idx];
        float w  = weight[c];
        float bb = bias[c];
        f32x4 o;
        o.x = w * (xv.x - mv.x) * iv.x + bb;
        o.y = w * (xv.y - mv.y) * iv.y + bb;
        o.z = w * (xv.z - mv.z) * iv.z + bb;
        o.w = w * (xv.w - mv.w) * iv.w + bb;
        __builtin_nontemporal_store(o, (f32x4*)&y4[idx]);
    }
}

extern "C" void kernel_launch(void* const* d_in, const int* in_sizes, int n_in,
                              void* d_out, int out_size, void* d_ws, size_t ws_size,
                              hipStream_t stream) {
    const float* x      = (const float*)d_in[0];
    const float* weight = (const float*)d_in[1];
    const float* bias   = (const float*)d_in[2];
    float* y = (float*)d_out;

    double2* agg = (double2*)d_ws;       // 1000 double2 = 16 KB

    const float4* x4 = (const float4*)x;
    float4* y4 = (float4*)y;
    void* args[] = { (void*)&x4, (void*)&weight, (void*)&bias,
                     (void*)&y4, (void*)&agg };
    hipLaunchCooperativeKernel((const void*)clnorm_coop,
                               dim3(B * NBLK), dim3(256), args, 0, stream);
}

// Round 8
// 83.821 us; speedup vs baseline: 2.0846x; 2.0846x over previous
//
#include <hip/hip_runtime.h>

#define EPS 1e-6

constexpr int B = 8, C = 256, T = 16000;
constexpr int T4 = T / 4;          // 4000
constexpr int BT = B * T;
constexpr int CS = 4;              // channel chunks for colsum
constexpr int CPC = C / CS;        // 64 channels per chunk

typedef float f32x4 __attribute__((ext_vector_type(4)));

// ---------------- Kernel 1: partial channel sums, float4 over t ----------------
// grid (16, CS, B) = 512 blocks, block 256. Each thread owns one float4 of t
// and loops 64 channels (unroll 8 -> 8 x 16B loads in flight = 8KB/wave,
// 4x the scalar version's MLP). Partials per channel-chunk; combined (in
// double) inside scan — deterministic, no atomics.
// Layout: Sp[cs][b][t], S2p[cs][b][t].
__global__ __launch_bounds__(256)
void colsum4_kernel(const float4* __restrict__ x4,
                    float* __restrict__ Sp, float* __restrict__ S2p) {
    int t4 = blockIdx.x * 256 + threadIdx.x;
    if (t4 >= T4) return;
    int cs = blockIdx.y;
    int b  = blockIdx.z;
    const float4* xp = x4 + ((size_t)b * C + (size_t)cs * CPC) * T4 + t4;
    float4 s = {0.f,0.f,0.f,0.f}, q = {0.f,0.f,0.f,0.f};
#pragma unroll 8
    for (int c = 0; c < CPC; ++c) {
        float4 v = xp[(size_t)c * T4];
        s.x += v.x;     s.y += v.y;     s.z += v.z;     s.w += v.w;
        q.x += v.x*v.x; q.y += v.y*v.y; q.z += v.z*v.z; q.w += v.w*v.w;
    }
    ((float4*)(Sp  + ((size_t)cs * B + b) * T))[t4] = s;
    ((float4*)(S2p + ((size_t)cs * B + b) * T))[t4] = q;
}

// ---------------- Kernel 2: combine partials + per-b scan -> mean, istd -------
// One block per b, 1024 threads, PT=16 elems/thread. Sums the CS partials in
// double, scans, then writes mean into Sp[0] region and istd into S2p[0]
// region (each element is read-then-written by its owning thread only).
__global__ __launch_bounds__(1024)
void scan_kernel(float* __restrict__ Sp, float* __restrict__ S2p) {
    constexpr int PT = 16;
    int b    = blockIdx.x;
    int tid  = threadIdx.x;
    int lane = tid & 63;
    int wid  = tid >> 6;
    int t0   = tid * PT;
    bool active = (t0 < T);

    double v[PT], v2[PT];
    if (active) {
        const float4* Sp4  = (const float4*)Sp;
        const float4* S2p4 = (const float4*)S2p;
#pragma unroll
        for (int j = 0; j < PT / 4; ++j) {
            double ax = 0, ay = 0, az = 0, aw = 0;
            double bx = 0, by = 0, bz = 0, bw = 0;
#pragma unroll
            for (int cs = 0; cs < CS; ++cs) {
                size_t base = ((size_t)cs * B + b) * T4 + (size_t)t0 / 4 + j;
                float4 a  = Sp4[base];
                float4 a2 = S2p4[base];
                ax += a.x;  ay += a.y;  az += a.z;  aw += a.w;
                bx += a2.x; by += a2.y; bz += a2.z; bw += a2.w;
            }
            v [4*j+0] = ax; v [4*j+1] = ay; v [4*j+2] = az; v [4*j+3] = aw;
            v2[4*j+0] = bx; v2[4*j+1] = by; v2[4*j+2] = bz; v2[4*j+3] = bw;
        }
    } else {
#pragma unroll
        for (int j = 0; j < PT; ++j) { v[j] = 0.0; v2[j] = 0.0; }
    }

    // thread-local inclusive scan
#pragma unroll
    for (int j = 1; j < PT; ++j) { v[j] += v[j-1]; v2[j] += v2[j-1]; }
    double ts = v[PT-1], ts2 = v2[PT-1];

    // wave-64 inclusive scan of thread totals
    double s = ts, s2 = ts2;
    for (int off = 1; off < 64; off <<= 1) {
        double u  = __shfl_up(s,  off);
        double u2 = __shfl_up(s2, off);
        if (lane >= off) { s += u; s2 += u2; }
    }
    double waveExcl  = s  - ts;
    double waveExcl2 = s2 - ts2;

    __shared__ double wtot[16], wtot2[16];
    if (lane == 63) { wtot[wid] = s; wtot2[wid] = s2; }
    __syncthreads();

    double base = 0.0, base2 = 0.0;
    for (int w = 0; w < wid; ++w) { base += wtot[w]; base2 += wtot2[w]; }
    double off0  = base  + waveExcl;
    double off02 = base2 + waveExcl2;

    if (active) {
        float m[PT], is[PT];
#pragma unroll
        for (int j = 0; j < PT; ++j) {
            double cs   = off0  + v[j];
            double cs2  = off02 + v2[j];
            double cnt  = (double)(t0 + j + 1) * (double)C;
            double mean = cs / cnt;
            double var  = cs2 / cnt - mean * mean;
            double istd = 1.0 / sqrt(var + EPS);
            m [j] = (float)mean;
            is[j] = (float)istd;
        }
        float4* mp = (float4*)(Sp  + (size_t)b * T + t0);   // overwrite cs=0 region
        float4* ip = (float4*)(S2p + (size_t)b * T + t0);
#pragma unroll
        for (int j = 0; j < PT / 4; ++j) {
            mp[j] = make_float4(m [4*j+0], m [4*j+1], m [4*j+2], m [4*j+3]);
            ip[j] = make_float4(is[4*j+0], is[4*j+1], is[4*j+2], is[4*j+3]);
        }
    }
}

// ---------------- Kernel 3: normalize, float4 over t (R6, proven) ------------
__global__ __launch_bounds__(256)
void norm_kernel(const float4* __restrict__ x4,
                 const float*  __restrict__ weight,
                 const float*  __restrict__ bias,
                 const float*  __restrict__ meanp,
                 const float*  __restrict__ istdp,
                 float4* __restrict__ y4) {
    int t4 = blockIdx.x * 256 + threadIdx.x;
    if (t4 >= T4) return;
    int c = blockIdx.y;
    int b = blockIdx.z;

    size_t idx = ((size_t)b * C + c) * T4 + t4;
    float4 xv = x4[idx];
    const float4 mv = *(const float4*)(meanp + (size_t)b * T + (size_t)t4 * 4);
    const float4 iv = *(const float4*)(istdp + (size_t)b * T + (size_t)t4 * 4);
    float w  = weight[c];
    float bb = bias[c];

    f32x4 o;
    o.x = w * (xv.x - mv.x) * iv.x + bb;
    o.y = w * (xv.y - mv.y) * iv.y + bb;
    o.z = w * (xv.z - mv.z) * iv.z + bb;
    o.w = w * (xv.w - mv.w) * iv.w + bb;
    __builtin_nontemporal_store(o, (f32x4*)&y4[idx]);
}

extern "C" void kernel_launch(void* const* d_in, const int* in_sizes, int n_in,
                              void* d_out, int out_size, void* d_ws, size_t ws_size,
                              hipStream_t stream) {
    const float* x      = (const float*)d_in[0];
    const float* weight = (const float*)d_in[1];
    const float* bias   = (const float*)d_in[2];
    float* y = (float*)d_out;

    float* Sp  = (float*)d_ws;           // CS*B*T floats = 2 MB
    float* S2p = Sp + (size_t)CS * BT;   // CS*B*T floats = 2 MB

    dim3 g1((T4 + 255) / 256, CS, B);    // 16 x 4 x 8 = 512 blocks
    colsum4_kernel<<<g1, 256, 0, stream>>>((const float4*)x, Sp, S2p);

    scan_kernel<<<B, 1024, 0, stream>>>(Sp, S2p);

    dim3 g3((T4 + 255) / 256, C, B);
    norm_kernel<<<g3, 256, 0, stream>>>((const float4*)x, weight, bias,
                                        Sp, S2p, (float4*)y);
}

// Round 9
// 74.100 us; speedup vs baseline: 2.3580x; 1.1312x over previous
//
#include <hip/hip_runtime.h>

#define EPS 1e-6

constexpr int B = 8, C = 256, T = 16000;
constexpr int T4 = T / 4;          // 4000, T divisible by 4
constexpr int BT = B * T;          // 128000

typedef float f32x4 __attribute__((ext_vector_type(4)));

// ---------------- Kernel 1: per-(b,t) channel sums ----------------
// grid (ceil(T/256), B), block 256. Lane-consecutive t => coalesced loads.
// Measured ~6.2 TB/s — at the read-only ceiling (R8's MLP variant regressed).
__global__ __launch_bounds__(256)
void colsum_kernel(const float* __restrict__ x,
                   float* __restrict__ S, float* __restrict__ S2) {
    int b = blockIdx.y;
    int t = blockIdx.x * 256 + threadIdx.x;
    if (t >= T) return;
    const float* xp = x + (size_t)b * C * T + t;
    float s = 0.f, s2 = 0.f;
#pragma unroll 8
    for (int c = 0; c < C; ++c) {
        float v = xp[(size_t)c * T];
        s  += v;
        s2 += v * v;
    }
    S [b * T + t] = s;
    S2[b * T + t] = s2;
}

// ---------------- Kernel 2: per-b inclusive scan -> mean, istd ----------------
// One block per b, 1024 threads. Single-pass: 16 elems/thread local scan
// (double), wave shfl-scan of thread totals, LDS pass over 16 wave totals.
// ~3 us, latency-bound; leave alone.
__global__ __launch_bounds__(1024)
void scan_kernel(const float* __restrict__ S, const float* __restrict__ S2,
                 float* __restrict__ meanp, float* __restrict__ istdp) {
    constexpr int PT = 16;                 // elements per thread; 1000 active
    int b    = blockIdx.x;
    int tid  = threadIdx.x;
    int lane = tid & 63;
    int wid  = tid >> 6;                   // 0..15
    int t0   = tid * PT;
    bool active = (t0 < T);

    double v[PT], v2[PT];
    if (active) {
        const float4* Sp  = (const float4*)(S  + b * T + t0);
        const float4* S2p = (const float4*)(S2 + b * T + t0);
#pragma unroll
        for (int j = 0; j < PT / 4; ++j) {
            float4 a  = Sp[j];
            float4 a2 = S2p[j];
            v [4*j+0] = a.x;  v [4*j+1] = a.y;  v [4*j+2] = a.z;  v [4*j+3] = a.w;
            v2[4*j+0] = a2.x; v2[4*j+1] = a2.y; v2[4*j+2] = a2.z; v2[4*j+3] = a2.w;
        }
    } else {
#pragma unroll
        for (int j = 0; j < PT; ++j) { v[j] = 0.0; v2[j] = 0.0; }
    }

    // thread-local inclusive scan
#pragma unroll
    for (int j = 1; j < PT; ++j) { v[j] += v[j-1]; v2[j] += v2[j-1]; }
    double ts = v[PT-1], ts2 = v2[PT-1];

    // wave-64 inclusive scan of thread totals
    double s = ts, s2 = ts2;
    for (int off = 1; off < 64; off <<= 1) {
        double u  = __shfl_up(s,  off);
        double u2 = __shfl_up(s2, off);
        if (lane >= off) { s += u; s2 += u2; }
    }
    double waveExcl  = s  - ts;
    double waveExcl2 = s2 - ts2;

    __shared__ double wtot[16], wtot2[16];
    if (lane == 63) { wtot[wid] = s; wtot2[wid] = s2; }
    __syncthreads();

    double base = 0.0, base2 = 0.0;
    for (int w = 0; w < wid; ++w) { base += wtot[w]; base2 += wtot2[w]; }
    double off0  = base  + waveExcl;
    double off02 = base2 + waveExcl2;

    if (active) {
        float m[PT], is[PT];
#pragma unroll
        for (int j = 0; j < PT; ++j) {
            double cs   = off0  + v[j];
            double cs2  = off02 + v2[j];
            double cnt  = (double)(t0 + j + 1) * (double)C;
            double mean = cs / cnt;
            double var  = cs2 / cnt - mean * mean;
            double istd = 1.0 / sqrt(var + EPS);
            m [j] = (float)mean;
            is[j] = (float)istd;
        }
        float4* mp = (float4*)(meanp + b * T + t0);
        float4* ip = (float4*)(istdp + b * T + t0);
#pragma unroll
        for (int j = 0; j < PT / 4; ++j) {
            mp[j] = make_float4(m [4*j+0], m [4*j+1], m [4*j+2], m [4*j+3]);
            ip[j] = make_float4(is[4*j+0], is[4*j+1], is[4*j+2], is[4*j+3]);
        }
    }
}

// ---------------- Kernel 3: normalize, float4 over t ----------------
// R2 structure + nontemporal y store (best measured: 74.0 us).
__global__ __launch_bounds__(256)
void norm_kernel(const float4* __restrict__ x4,
                 const float*  __restrict__ weight,
                 const float*  __restrict__ bias,
                 const float*  __restrict__ meanp,
                 const float*  __restrict__ istdp,
                 float4* __restrict__ y4) {
    int t4 = blockIdx.x * 256 + threadIdx.x;
    if (t4 >= T4) return;
    int c = blockIdx.y;
    int b = blockIdx.z;

    size_t idx = ((size_t)b * C + c) * T4 + t4;
    float4 xv = x4[idx];
    const float4 mv = *(const float4*)(meanp + (size_t)b * T + (size_t)t4 * 4);
    const float4 iv = *(const float4*)(istdp + (size_t)b * T + (size_t)t4 * 4);
    float w  = weight[c];
    float bb = bias[c];

    f32x4 o;
    o.x = w * (xv.x - mv.x) * iv.x + bb;
    o.y = w * (xv.y - mv.y) * iv.y + bb;
    o.z = w * (xv.z - mv.z) * iv.z + bb;
    o.w = w * (xv.w - mv.w) * iv.w + bb;
    __builtin_nontemporal_store(o, (f32x4*)&y4[idx]);
}

extern "C" void kernel_launch(void* const* d_in, const int* in_sizes, int n_in,
                              void* d_out, int out_size, void* d_ws, size_t ws_size,
                              hipStream_t stream) {
    const float* x      = (const float*)d_in[0];
    const float* weight = (const float*)d_in[1];
    const float* bias   = (const float*)d_in[2];
    float* y = (float*)d_out;

    float* S    = (float*)d_ws;          // BT floats
    float* S2   = S  + BT;               // BT floats
    float* mea  = S2 + BT;               // BT floats
    float* istd = mea + BT;              // BT floats  (total 2 MB)

    dim3 g1((T + 255) / 256, B);
    colsum_kernel<<<g1, 256, 0, stream>>>(x, S, S2);

    scan_kernel<<<B, 1024, 0, stream>>>(S, S2, mea, istd);

    dim3 g3((T4 + 255) / 256, C, B);
    norm_kernel<<<g3, 256, 0, stream>>>((const float4*)x, weight, bias,
                                        mea, istd, (float4*)y);
}